// Round 9
// baseline (305.861 us; speedup 1.0000x reference)
//
#include <hip/hip_runtime.h>
#include <hip/hip_bf16.h>
#include <cstdint>

// ============================================================================
// ScaledDotAttention: out = softmax((Q Wq^T + bq)(K Wk^T + bk)^T / 8) @ V
// B=8, N=4096, DK=512, DM=64.
// R9: R5 skeleton, hardened + pk-LDS removed.
//     - vt staged via global_load_lds dbuf; DMA drained by vmcnt(0) BEFORE
//       bar2 (cross-wave-safe by construction; no counted vmcnt anywhere).
//     - pk fragments loaded straight into registers (private, race-free),
//       issued at step top for use in qkt (kh=1 waves hide them under PV).
//     - LDS = vt dbuf 128K + P 16K = 144.5KB.
//     - fixed-max exp2 softmax, staggered wave roles, cvtpk P-pack.
// ============================================================================

#define DEVINL __device__ __forceinline__

using f32x4  = __attribute__((ext_vector_type(4)))  float;
using bf16x8 = __attribute__((ext_vector_type(8)))  short;
using bf16x4 = __attribute__((ext_vector_type(4)))  short;

constexpr int BATCH = 8;
constexpr int N     = 4096;
constexpr int DK    = 512;
constexpr int DM    = 64;
constexpr int KVB   = 64;
constexpr int QB    = 128;
constexpr int STEPS = N / KVB;       // 64

// log2(e)/8 folded into pq so scores are in exp2 domain
#define PQ_SCALE 0.18033688011112042f
#define FM 10.0f

DEVINL short cvt_bf16(float x) {
  uint32_t u = __float_as_uint(x);
  uint32_t r = u + 0x7fffu + ((u >> 16) & 1u);
  return (short)(r >> 16);
}

DEVINL uint32_t cvtpk(float lo, float hi) {
  uint32_t r;
  asm("v_cvt_pk_bf16_f32 %0, %1, %2" : "=v"(r) : "v"(lo), "v"(hi));
  return r;
}

DEVINL void async16(void* lds, const void* g) {
  __builtin_amdgcn_global_load_lds(
      (const __attribute__((address_space(1))) uint32_t*)(uintptr_t)g,
      (__attribute__((address_space(3))) uint32_t*)(uint32_t)(uintptr_t)lds,
      16, 0, 0);
}

DEVINL f32x4 mfma16(bf16x8 a, bf16x8 b, f32x4 c) {
  return __builtin_amdgcn_mfma_f32_16x16x32_bf16(a, b, c, 0, 0, 0);
}

#define LGKM0_BAR() do { \
  asm volatile("s_waitcnt lgkmcnt(0)" ::: "memory"); \
  __builtin_amdgcn_s_barrier(); \
} while (0)

// full drain barrier: publishes LDS writes AND in-flight LDS-DMA to all waves
#define FULL_BAR() do { \
  asm volatile("s_waitcnt vmcnt(0) lgkmcnt(0)" ::: "memory"); \
  __builtin_amdgcn_s_barrier(); \
} while (0)

// ---------------------------------------------------------------------------
__global__ __launch_bounds__(256) void wconv_kernel(
    const float* __restrict__ Wk, const float* __restrict__ Wq,
    short* __restrict__ WkB, short* __restrict__ WqB) {
  int i = blockIdx.x * 256 + threadIdx.x;
  WkB[i] = cvt_bf16(Wk[i]);
  WqB[i] = cvt_bf16(Wq[i]);
}

// ---------------------------------------------------------------------------
__global__ __launch_bounds__(256) void vtrans_kernel(
    const float* __restrict__ V, short* __restrict__ Vt) {
  int bb = blockIdx.x;
  int b  = bb >> 9;
  int nt = (bb >> 3) & 63;
  int dt = bb & 7;
  int n0 = nt * 64, d0 = dt * 64;
  __shared__ short t_lds[64][80];
  int tid = threadIdx.x;
#pragma unroll
  for (int it = 0; it < 4; ++it) {
    int idx = it * 256 + tid;
    int row = idx >> 4;
    int c4  = idx & 15;
    f32x4 v = *(const f32x4*)&V[((size_t)b * N + n0 + row) * DK + d0 + c4 * 4];
#pragma unroll
    for (int j = 0; j < 4; ++j) t_lds[c4 * 4 + j][row] = cvt_bf16(v[j]);
  }
  __syncthreads();
#pragma unroll
  for (int it = 0; it < 2; ++it) {
    int idx = it * 256 + tid;
    int rd = idx >> 3;
    int ck = idx & 7;
    bf16x8 vv = *(const bf16x8*)&t_lds[rd][ck * 8];
    *(bf16x8*)&Vt[((size_t)b * DK + d0 + rd) * N + n0 + ck * 8] = vv;
  }
}

// ---------------------------------------------------------------------------
__global__ __launch_bounds__(512, 2) void proj_kernel(
    const float* __restrict__ Q, const float* __restrict__ K,
    const short* __restrict__ WqB, const short* __restrict__ WkB,
    const float* __restrict__ bq, const float* __restrict__ bk,
    short* __restrict__ pq, short* __restrict__ pk) {
  bool isK = blockIdx.x >= 256;
  const float* X    = isK ? K : Q;
  const short* W    = isK ? WkB : WqB;
  const float* bias = isK ? bk : bq;
  short* P          = isK ? pk : pq;
  float sc          = isK ? 1.0f : PQ_SCALE;
  int rb = (blockIdx.x & 255) * 128;

  __shared__ short x_lds[128 * 512];
  int tid = threadIdx.x, w = tid >> 6, lane = tid & 63, g = lane >> 4, c = lane & 15;

#pragma unroll
  for (int it = 0; it < 32; ++it) {
    int idx4 = it * 512 + tid;
    int row  = idx4 >> 7;
    int col  = (idx4 & 127) * 4;
    f32x4 v = *(const f32x4*)&X[((size_t)rb + row) * DK + col];
    bf16x4 hb;
#pragma unroll
    for (int j = 0; j < 4; ++j) hb[j] = cvt_bf16(v[j]);
    int scz = (col >> 3) ^ (row & 7);
    *(bf16x4*)&x_lds[row * 512 + scz * 8 + ((col >> 2) & 1) * 4] = hb;
  }
  __syncthreads();

  f32x4 o[4];
#pragma unroll
  for (int mt = 0; mt < 4; ++mt) o[mt] = f32x4{0.f, 0.f, 0.f, 0.f};
  int arow = w * 16 + c;
#pragma unroll
  for (int ks = 0; ks < 16; ++ks) {
    int scz = (ks * 4 + g) ^ (arow & 7);
    bf16x8 a = *(const bf16x8*)&x_lds[arow * 512 + scz * 8];
#pragma unroll
    for (int mt = 0; mt < 4; ++mt) {
      bf16x8 bfr = *(const bf16x8*)&W[(size_t)(mt * 16 + c) * DK + ks * 32 + g * 8];
      o[mt] = mfma16(a, bfr, o[mt]);
    }
  }
#pragma unroll
  for (int mt = 0; mt < 4; ++mt) {
    float bb = bias[mt * 16 + c];
#pragma unroll
    for (int r = 0; r < 4; ++r) {
      int row = rb + w * 16 + g * 4 + r;
      P[(size_t)row * DM + mt * 16 + c] = cvt_bf16((o[mt][r] + bb) * sc);
    }
  }
}

// ---------------------------------------------------------------------------
__global__ __launch_bounds__(512, 2) void flash_kernel(
    const short* __restrict__ pq, const short* __restrict__ pk,
    const short* __restrict__ vt, float* __restrict__ out) {
  int b  = blockIdx.x & 7;             // batch -> XCD (L2-local vt/pk)
  int qt = blockIdx.x >> 3;
  int q0 = qt * QB;

  int tid = threadIdx.x, w = tid >> 6, lane = tid & 63, g = lane >> 4, c = lane & 15;
  int qrow = w * 16 + c;
  int cs = c & 7;
  int kh = w >> 2;                     // stagger selector

  __shared__ short vt_lds[2][DK * KVB];         // 128KB dbuf
  __shared__ short p_lds[QB * KVB];             // 16KB
  __shared__ float lsum_lds[QB];

  // ------- invariant LDS pointers -----------------------------------------
  const short* pfr0 = p_lds + c * 64 + ((g ^ cs) * 8);
  const short* pfr1 = p_lds + c * 64 + (((4 + g) ^ cs) * 8);
  const short* vfA0 = &vt_lds[0][(w * 64 + c) * 64 + ((g ^ cs) * 8)];
  const short* vfA1 = &vt_lds[0][(w * 64 + c) * 64 + (((4 + g) ^ cs) * 8)];
  const short* vfB0 = vfA0 + DK * KVB;
  const short* vfB1 = vfA1 + DK * KVB;
  short* pw0 = p_lds + qrow * 64 + ((((g >> 1) + 0) ^ cs) * 8) + (g & 1) * 4;
  short* pw1 = p_lds + qrow * 64 + ((((g >> 1) + 2) ^ cs) * 8) + (g & 1) * 4;
  short* pw2 = p_lds + qrow * 64 + ((((g >> 1) + 4) ^ cs) * 8) + (g & 1) * 4;
  short* pw3 = p_lds + qrow * 64 + ((((g >> 1) + 6) ^ cs) * 8) + (g & 1) * 4;

  // ------- vt staging (global_load_lds, pre-swizzled src, linear dst) ------
  const short* vt_base = vt + (size_t)b * DK * N;
  int tr = tid >> 3, tc = tid & 7;
  int vt_vo[8];
#pragma unroll
  for (int r = 0; r < 8; ++r)
    vt_vo[r] = (r * 64 + tr) * N + ((tc ^ (tr & 7)) * 8);
  short* vt_dst0 = &vt_lds[0][w * 512];
  short* vt_dst1 = &vt_lds[1][w * 512];
  auto stage_vt = [&](short* vdst) {
#pragma unroll
    for (int r = 0; r < 8; ++r)
      async16((void*)(vdst + r * 4096), (const void*)(vt_base + vt_vo[r]));
    vt_base += KVB;
  };

  // ------- pk fragments: straight to registers (private, race-free) -------
  // frag (s,h): pk[(t*64 + s*16 + c)*64 + (h*4+g)*8]
  const short* pk_src = pk + (size_t)b * N * DM + (size_t)c * DM + g * 8;

  // ------- pq fragments ----------------------------------------------------
  const short* pq_row = pq + ((size_t)b * N + q0 + qrow) * DM;
  bf16x8 qf0 = *(const bf16x8*)(pq_row + g * 8);
  bf16x8 qf1 = *(const bf16x8*)(pq_row + 32 + g * 8);

  f32x4 acc[4][8];
#pragma unroll
  for (int i = 0; i < 4; ++i)
#pragma unroll
    for (int j = 0; j < 8; ++j) acc[i][j] = f32x4{0.f, 0.f, 0.f, 0.f};

  float lp = 0.f;
  uint32_t pbu[8];

  auto qkt_smax = [&](const bf16x8* pkf0, const bf16x8* pkf1) {
#pragma unroll
    for (int s = 0; s < 4; ++s) {
      f32x4 d = f32x4{-FM, -FM, -FM, -FM};
      d = mfma16(pkf0[s], qf0, d);
      d = mfma16(pkf1[s], qf1, d);
      float p0 = exp2f(d[0]), p1 = exp2f(d[1]);
      float p2 = exp2f(d[2]), p3 = exp2f(d[3]);
      lp += (p0 + p1) + (p2 + p3);
      pbu[s * 2]     = cvtpk(p0, p1);
      pbu[s * 2 + 1] = cvtpk(p2, p3);
    }
  };

  auto pv = [&](const short* vf0, const short* vf1) {
    __builtin_amdgcn_s_setprio(1);
    {
      bf16x8 pf[8];
#pragma unroll
      for (int j = 0; j < 8; ++j) pf[j] = *(const bf16x8*)(pfr0 + j * 1024);
#pragma unroll
      for (int i = 0; i < 4; ++i) {
        bf16x8 vfr = *(const bf16x8*)(vf0 + i * 1024);
#pragma unroll
        for (int j = 0; j < 8; ++j) acc[i][j] = mfma16(vfr, pf[j], acc[i][j]);
      }
    }
    {
      bf16x8 pf[8];
#pragma unroll
      for (int j = 0; j < 8; ++j) pf[j] = *(const bf16x8*)(pfr1 + j * 1024);
#pragma unroll
      for (int i = 0; i < 4; ++i) {
        bf16x8 vfr = *(const bf16x8*)(vf1 + i * 1024);
#pragma unroll
        for (int j = 0; j < 8; ++j) acc[i][j] = mfma16(vfr, pf[j], acc[i][j]);
      }
    }
    __builtin_amdgcn_s_setprio(0);
  };

  auto publish_p = [&]() {
    *(uint32_t*)pw0 = pbu[0]; *(uint32_t*)(pw0 + 2) = pbu[1];
    *(uint32_t*)pw1 = pbu[2]; *(uint32_t*)(pw1 + 2) = pbu[3];
    *(uint32_t*)pw2 = pbu[4]; *(uint32_t*)(pw2 + 2) = pbu[5];
    *(uint32_t*)pw3 = pbu[6]; *(uint32_t*)(pw3 + 2) = pbu[7];
  };

  // ========================= prolog ========================================
  stage_vt(vt_dst0);                   // vt(0)
  {
    bf16x8 pkf0[4], pkf1[4];
#pragma unroll
    for (int s = 0; s < 4; ++s) {
      pkf0[s] = *(const bf16x8*)(pk_src + s * 1024);
      pkf1[s] = *(const bf16x8*)(pk_src + s * 1024 + 32);
    }
    pk_src += KVB * DM;
    qkt_smax(pkf0, pkf1);              // S(0)
    publish_p();                       // P(0)
  }
  FULL_BAR();                          // vt(0) DMA drained + P(0) visible
  __builtin_amdgcn_sched_barrier(0);

  // ========================= main loop: PV(t) + QKT(t+1) ===================
  for (int t = 0; t < STEPS - 1; ++t) {
    int vb = t & 1;
    stage_vt(vb ? vt_dst0 : vt_dst1);  // vt(t+1) DMA, drained at FULL_BAR below

    bf16x8 pkf0[4], pkf1[4];           // pk(t+1) frags -> regs (private)
#pragma unroll
    for (int s = 0; s < 4; ++s) {
      pkf0[s] = *(const bf16x8*)(pk_src + s * 1024);
      pkf1[s] = *(const bf16x8*)(pk_src + s * 1024 + 32);
    }
    pk_src += KVB * DM;
    __builtin_amdgcn_sched_barrier(0);

    const short* vf0 = vb ? vfB0 : vfA0;
    const short* vf1 = vb ? vfB1 : vfA1;

    // staggered roles: SIMD-paired waves (w, w+4) take opposite orders
    if (kh == 0) {
      qkt_smax(pkf0, pkf1);            // QKT(t+1), no LDS dependency
      pv(vf0, vf1);                    // PV(t)
    } else {
      pv(vf0, vf1);                    // pkf loads hidden under PV
      qkt_smax(pkf0, pkf1);
    }

    LGKM0_BAR();                       // barrier 1: all p_lds reads done
    __builtin_amdgcn_sched_barrier(0);

    publish_p();                       // P(t+1)
    FULL_BAR();                        // barrier 2: P writes + vt DMA published
    __builtin_amdgcn_sched_barrier(0);
  }

  // ========================= epilog: PV(last) ==============================
  {
    int vb = (STEPS - 1) & 1;
    pv(vb ? vfB0 : vfA0, vb ? vfB1 : vfA1);
  }

  // l reduce
  lp += __shfl_xor(lp, 16);
  lp += __shfl_xor(lp, 32);
  if (g == 0) lsum_lds[qrow] = lp;
  LGKM0_BAR();

  float* out_b = out + (size_t)b * N * DK;
#pragma unroll
  for (int j = 0; j < 8; ++j) {
    float rl = 1.f / lsum_lds[j * 16 + c];
    int q = q0 + j * 16 + c;
#pragma unroll
    for (int i = 0; i < 4; ++i) {
      f32x4 o = acc[i][j];
      o[0] *= rl; o[1] *= rl; o[2] *= rl; o[3] *= rl;
      *(f32x4*)&out_b[(size_t)q * DK + w * 64 + i * 16 + g * 4] = o;
    }
  }
}

// ---------------------------------------------------------------------------
extern "C" void kernel_launch(void* const* d_in, const int* in_sizes, int n_in,
                              void* d_out, int out_size, void* d_ws, size_t ws_size,
                              hipStream_t stream) {
  (void)in_sizes; (void)n_in; (void)out_size; (void)ws_size;
  const float* K  = (const float*)d_in[0];
  const float* Q  = (const float*)d_in[1];
  const float* V  = (const float*)d_in[2];
  const float* Wk = (const float*)d_in[3];
  const float* bk = (const float*)d_in[4];
  const float* Wq = (const float*)d_in[5];
  const float* bq = (const float*)d_in[6];
  float* out = (float*)d_out;

  char* ws = (char*)d_ws;
  short* pq  = (short*)(ws + 0);
  short* pk  = (short*)(ws + ((size_t)4 << 20));
  short* vt  = (short*)(ws + ((size_t)8 << 20));
  short* WqB = (short*)(ws + ((size_t)40 << 20));
  short* WkB = (short*)(ws + ((size_t)40 << 20) + 64 * 512 * 2);

  hipLaunchKernelGGL(wconv_kernel,  dim3(128),  dim3(256), 0, stream, Wk, Wq, WkB, WqB);
  hipLaunchKernelGGL(vtrans_kernel, dim3(4096), dim3(256), 0, stream, V, vt);
  hipLaunchKernelGGL(proj_kernel,   dim3(512),  dim3(512), 0, stream, Q, K, WqB, WkB, bq, bk, pq, pk);
  hipLaunchKernelGGL(flash_kernel,  dim3(256),  dim3(512), 0, stream, pq, pk, vt, out);
}

// Round 10
// 265.351 us; speedup vs baseline: 1.1527x; 1.1527x over previous
//
#include <hip/hip_runtime.h>
#include <hip/hip_bf16.h>
#include <cstdint>

// ============================================================================
// ScaledDotAttention: out = softmax((Q Wq^T + bq)(K Wk^T + bk)^T / 8) @ V
// B=8, N=4096, DK=512, DM=64.
// R10: R5 skeleton (LDS-staged vt dbuf via global_load_lds, counted vmcnt,
//      lgkm-only barriers, fixed-max exp2 softmax, stagger) retiled to
//      16 waves/block (1024 thr) @ 4 waves/SIMD:
//      - pv role (vh,vs): 64 vcols x 64 q per wave -> acc[4][4] = 64 VGPR
//      - qkt role (qg,kqh): 16 q x 32 keys per wave (2 key-tiles, 4 MFMAs)
//      - pk reg-staged 8B/thread (load BEFORE stage_vt -> region-B write
//        waits only pk; vmcnt(5) at top drains exactly vt(t))
// ============================================================================

#define DEVINL __device__ __forceinline__

using f32x4  = __attribute__((ext_vector_type(4)))  float;
using bf16x8 = __attribute__((ext_vector_type(8)))  short;
using bf16x4 = __attribute__((ext_vector_type(4)))  short;

constexpr int BATCH = 8;
constexpr int N     = 4096;
constexpr int DK    = 512;
constexpr int DM    = 64;
constexpr int KVB   = 64;
constexpr int QB    = 128;
constexpr int STEPS = N / KVB;       // 64

// log2(e)/8 folded into pq so scores are in exp2 domain
#define PQ_SCALE 0.18033688011112042f
#define FM 10.0f

DEVINL short cvt_bf16(float x) {
  uint32_t u = __float_as_uint(x);
  uint32_t r = u + 0x7fffu + ((u >> 16) & 1u);
  return (short)(r >> 16);
}

DEVINL uint32_t cvtpk(float lo, float hi) {
  uint32_t r;
  asm("v_cvt_pk_bf16_f32 %0, %1, %2" : "=v"(r) : "v"(lo), "v"(hi));
  return r;
}

DEVINL void async16(void* lds, const void* g) {
  __builtin_amdgcn_global_load_lds(
      (const __attribute__((address_space(1))) uint32_t*)(uintptr_t)g,
      (__attribute__((address_space(3))) uint32_t*)(uint32_t)(uintptr_t)lds,
      16, 0, 0);
}

DEVINL f32x4 mfma16(bf16x8 a, bf16x8 b, f32x4 c) {
  return __builtin_amdgcn_mfma_f32_16x16x32_bf16(a, b, c, 0, 0, 0);
}

#define LGKM0_BAR() do { \
  asm volatile("s_waitcnt lgkmcnt(0)" ::: "memory"); \
  __builtin_amdgcn_s_barrier(); \
} while (0)

// ---------------------------------------------------------------------------
__global__ __launch_bounds__(256) void wconv_kernel(
    const float* __restrict__ Wk, const float* __restrict__ Wq,
    short* __restrict__ WkB, short* __restrict__ WqB) {
  int i = blockIdx.x * 256 + threadIdx.x;
  WkB[i] = cvt_bf16(Wk[i]);
  WqB[i] = cvt_bf16(Wq[i]);
}

// ---------------------------------------------------------------------------
__global__ __launch_bounds__(256) void vtrans_kernel(
    const float* __restrict__ V, short* __restrict__ Vt) {
  int bb = blockIdx.x;
  int b  = bb >> 9;
  int nt = (bb >> 3) & 63;
  int dt = bb & 7;
  int n0 = nt * 64, d0 = dt * 64;
  __shared__ short t_lds[64][80];
  int tid = threadIdx.x;
#pragma unroll
  for (int it = 0; it < 4; ++it) {
    int idx = it * 256 + tid;
    int row = idx >> 4;
    int c4  = idx & 15;
    f32x4 v = *(const f32x4*)&V[((size_t)b * N + n0 + row) * DK + d0 + c4 * 4];
#pragma unroll
    for (int j = 0; j < 4; ++j) t_lds[c4 * 4 + j][row] = cvt_bf16(v[j]);
  }
  __syncthreads();
#pragma unroll
  for (int it = 0; it < 2; ++it) {
    int idx = it * 256 + tid;
    int rd = idx >> 3;
    int ck = idx & 7;
    bf16x8 vv = *(const bf16x8*)&t_lds[rd][ck * 8];
    *(bf16x8*)&Vt[((size_t)b * DK + d0 + rd) * N + n0 + ck * 8] = vv;
  }
}

// ---------------------------------------------------------------------------
__global__ __launch_bounds__(512, 2) void proj_kernel(
    const float* __restrict__ Q, const float* __restrict__ K,
    const short* __restrict__ WqB, const short* __restrict__ WkB,
    const float* __restrict__ bq, const float* __restrict__ bk,
    short* __restrict__ pq, short* __restrict__ pk) {
  bool isK = blockIdx.x >= 256;
  const float* X    = isK ? K : Q;
  const short* W    = isK ? WkB : WqB;
  const float* bias = isK ? bk : bq;
  short* P          = isK ? pk : pq;
  float sc          = isK ? 1.0f : PQ_SCALE;
  int rb = (blockIdx.x & 255) * 128;

  __shared__ short x_lds[128 * 512];
  int tid = threadIdx.x, w = tid >> 6, lane = tid & 63, g = lane >> 4, c = lane & 15;

#pragma unroll
  for (int it = 0; it < 32; ++it) {
    int idx4 = it * 512 + tid;
    int row  = idx4 >> 7;
    int col  = (idx4 & 127) * 4;
    f32x4 v = *(const f32x4*)&X[((size_t)rb + row) * DK + col];
    bf16x4 hb;
#pragma unroll
    for (int j = 0; j < 4; ++j) hb[j] = cvt_bf16(v[j]);
    int scz = (col >> 3) ^ (row & 7);
    *(bf16x4*)&x_lds[row * 512 + scz * 8 + ((col >> 2) & 1) * 4] = hb;
  }
  __syncthreads();

  f32x4 o[4];
#pragma unroll
  for (int mt = 0; mt < 4; ++mt) o[mt] = f32x4{0.f, 0.f, 0.f, 0.f};
  int arow = w * 16 + c;
#pragma unroll
  for (int ks = 0; ks < 16; ++ks) {
    int scz = (ks * 4 + g) ^ (arow & 7);
    bf16x8 a = *(const bf16x8*)&x_lds[arow * 512 + scz * 8];
#pragma unroll
    for (int mt = 0; mt < 4; ++mt) {
      bf16x8 bfr = *(const bf16x8*)&W[(size_t)(mt * 16 + c) * DK + ks * 32 + g * 8];
      o[mt] = mfma16(a, bfr, o[mt]);
    }
  }
#pragma unroll
  for (int mt = 0; mt < 4; ++mt) {
    float bb = bias[mt * 16 + c];
#pragma unroll
    for (int r = 0; r < 4; ++r) {
      int row = rb + w * 16 + g * 4 + r;
      P[(size_t)row * DM + mt * 16 + c] = cvt_bf16((o[mt][r] + bb) * sc);
    }
  }
}

// ---------------------------------------------------------------------------
__global__ __launch_bounds__(1024, 4) void flash_kernel(
    const short* __restrict__ pq, const short* __restrict__ pk,
    const short* __restrict__ vt, float* __restrict__ out) {
  int b  = blockIdx.x & 7;             // batch -> XCD (L2-local vt/pk)
  int qt = blockIdx.x >> 3;            // 0..31
  int q0 = qt * QB;

  int tid = threadIdx.x, w = tid >> 6, lane = tid & 63, g = lane >> 4, c = lane & 15;
  int cs = c & 7;
  // qkt role: 16 q-rows (qg) x 32 keys (kqh half)
  int qg = w & 7, kqh = w >> 3;
  int qrow = qg * 16 + c;
  // pv role: 64 vcols (vs) x 64 q (vh half)
  int vh = w >> 3, vs = w & 7;

  __shared__ short vt_lds[2][DK * KVB];         // 128KB dbuf
  __shared__ short pk_lds[KVB * DM];            //  8KB
  __shared__ short p_lds[QB * KVB];             // 16KB
  __shared__ float lsum2[2][QB];

  // ------- qkt LDS pointers (imm offsets for s-tiles) ----------------------
  const short* pkr0 = pk_lds + (kqh * 32 + c) * 64 + ((g ^ cs) * 8);
  const short* pkr1 = pk_lds + (kqh * 32 + c) * 64 + (((4 + g) ^ cs) * 8);
  // P write: chunk = kqh*4 + s*2 + (g>>1), s in {0,1}
  short* pw0 = p_lds + qrow * 64 + (((kqh * 4 + 0 + (g >> 1)) ^ cs) * 8) + (g & 1) * 4;
  short* pw1 = p_lds + qrow * 64 + (((kqh * 4 + 2 + (g >> 1)) ^ cs) * 8) + (g & 1) * 4;

  // ------- pv LDS pointers -------------------------------------------------
  const short* pfr0 = p_lds + (vh * 64 + c) * 64 + ((g ^ cs) * 8);
  const short* pfr1 = p_lds + (vh * 64 + c) * 64 + (((4 + g) ^ cs) * 8);
  const short* vfA0 = &vt_lds[0][(vs * 64 + c) * 64 + ((g ^ cs) * 8)];
  const short* vfA1 = &vt_lds[0][(vs * 64 + c) * 64 + (((4 + g) ^ cs) * 8)];
  const short* vfB0 = vfA0 + DK * KVB;
  const short* vfB1 = vfA1 + DK * KVB;

  // ------- vt staging: 4 x async16 per thread (64KB tile) ------------------
  const short* vt_base = vt + (size_t)b * DK * N;
  int tr = tid >> 3, tc = tid & 7;
  int vt_vo[4];
#pragma unroll
  for (int r = 0; r < 4; ++r) {
    int row = r * 128 + tr;            // vcol 0..511
    vt_vo[r] = row * N + ((tc ^ (tr & 7)) * 8);
  }
  short* vt_dst0 = &vt_lds[0][w * 512];
  short* vt_dst1 = &vt_lds[1][w * 512];
  auto stage_vt = [&](short* vdst) {
#pragma unroll
    for (int r = 0; r < 4; ++r)
      async16((void*)(vdst + r * 8192), (const void*)(vt_base + vt_vo[r]));
    vt_base += KVB;
  };

  // ------- pk reg-staging: 8B per thread (all 1024 threads) ----------------
  // element idx8 = tid: key row = tid>>4, h = tid&15 (8B half-chunk)
  const short* pk_base = pk + (size_t)b * N * DM;
  {
    int prow = tid >> 4, h = tid & 15;
    pk_base += prow * 64 + (((h >> 1) ^ (prow & 7)) * 8) + (h & 1) * 4;
  }
  short* pk_wr = pk_lds + tid * 4;     // linear 8B/thread dest (swizzled layout)
  bf16x4 pkreg;

  // ------- pq fragments ----------------------------------------------------
  const short* pq_row = pq + ((size_t)b * N + q0 + qrow) * DM;
  bf16x8 qf0 = *(const bf16x8*)(pq_row + g * 8);
  bf16x8 qf1 = *(const bf16x8*)(pq_row + 32 + g * 8);

  f32x4 acc[4][4];
#pragma unroll
  for (int i = 0; i < 4; ++i)
#pragma unroll
    for (int j = 0; j < 4; ++j) acc[i][j] = f32x4{0.f, 0.f, 0.f, 0.f};

  float lp = 0.f;
  uint32_t pbu[4];

  auto qkt_smax = [&]() {
#pragma unroll
    for (int s = 0; s < 2; ++s) {
      bf16x8 a0 = *(const bf16x8*)(pkr0 + s * 1024);
      bf16x8 a1 = *(const bf16x8*)(pkr1 + s * 1024);
      f32x4 d = f32x4{-FM, -FM, -FM, -FM};
      d = mfma16(a0, qf0, d);
      d = mfma16(a1, qf1, d);
      float p0 = exp2f(d[0]), p1 = exp2f(d[1]);
      float p2 = exp2f(d[2]), p3 = exp2f(d[3]);
      lp += (p0 + p1) + (p2 + p3);
      pbu[s * 2]     = cvtpk(p0, p1);
      pbu[s * 2 + 1] = cvtpk(p2, p3);
    }
  };

  auto pv = [&](const short* vf0p, const short* vf1p) {
    __builtin_amdgcn_s_setprio(1);
    {
      bf16x8 vf[4];
#pragma unroll
      for (int i = 0; i < 4; ++i) vf[i] = *(const bf16x8*)(vf0p + i * 1024);
#pragma unroll
      for (int j = 0; j < 4; ++j) {
        bf16x8 pf = *(const bf16x8*)(pfr0 + j * 1024);
#pragma unroll
        for (int i = 0; i < 4; ++i) acc[i][j] = mfma16(vf[i], pf, acc[i][j]);
      }
    }
    {
      bf16x8 vf[4];
#pragma unroll
      for (int i = 0; i < 4; ++i) vf[i] = *(const bf16x8*)(vf1p + i * 1024);
#pragma unroll
      for (int j = 0; j < 4; ++j) {
        bf16x8 pf = *(const bf16x8*)(pfr1 + j * 1024);
#pragma unroll
        for (int i = 0; i < 4; ++i) acc[i][j] = mfma16(vf[i], pf, acc[i][j]);
      }
    }
    __builtin_amdgcn_s_setprio(0);
  };

  auto publish_p = [&]() {
    *(uint2*)pw0 = uint2{pbu[0], pbu[1]};
    *(uint2*)pw1 = uint2{pbu[2], pbu[3]};
  };

  // ========================= prolog ========================================
  stage_vt(vt_dst0);                   // vt(0) DMA
  pkreg = *(const bf16x4*)pk_base;     // pk(0)
  pk_base += KVB * DM;
  *(bf16x4*)pk_wr = pkreg;             // compiler inserts vm wait
  __syncthreads();                     // full drain: vt(0)+pk(0) visible

  qkt_smax();                          // S(0)
  pkreg = *(const bf16x4*)pk_base;     // pk(1)
  pk_base += KVB * DM;
  LGKM0_BAR();                         // all pk(0) reads done
  publish_p();                         // P(0)
  *(bf16x4*)pk_wr = pkreg;             // pk(1)
  LGKM0_BAR();                         // P(0)+pk(1) visible
  __builtin_amdgcn_sched_barrier(0);

  // ========================= main loop: PV(t) + QKT(t+1) ===================
  for (int t = 0; t < STEPS - 1; ++t) {
    int vb = t & 1;
    pkreg = *(const bf16x4*)pk_base;   // pk(t+2) (oldest VM op this step)
    pk_base += KVB * DM;
    stage_vt(vb ? vt_dst0 : vt_dst1);  // vt(t+1), 4 DMA ops
    // queue: [vt(t):4, pk:1, vt(t+1):4] -> drain 4 oldest = vt(t)
    asm volatile("s_waitcnt vmcnt(5)" ::: "memory");
    __builtin_amdgcn_sched_barrier(0);

    const short* vf0 = vb ? vfB0 : vfA0;
    const short* vf1 = vb ? vfB1 : vfA1;

    // staggered roles: SIMD gets kqh {0,0,1,1}
    if (kqh == 0) {
      qkt_smax();                      // QKT(t+1) from LDS
      pv(vf0, vf1);                    // PV(t)
    } else {
      pv(vf0, vf1);
      qkt_smax();
    }

    LGKM0_BAR();                       // barrier 1: all p/pk LDS reads done
    __builtin_amdgcn_sched_barrier(0);

    if (t < STEPS - 2) *(bf16x4*)pk_wr = pkreg;  // stage pk(t+2)
    publish_p();                                  // P(t+1)
    LGKM0_BAR();                       // barrier 2: writes visible
    __builtin_amdgcn_sched_barrier(0);
  }

  // ========================= epilog: PV(last) ==============================
  asm volatile("s_waitcnt vmcnt(0)" ::: "memory");
  __builtin_amdgcn_sched_barrier(0);
  {
    int vb = (STEPS - 1) & 1;
    pv(vb ? vfB0 : vfA0, vb ? vfB1 : vfA1);
  }

  // l reduce: lane partials (within kqh half) -> per-q half-sums
  lp += __shfl_xor(lp, 16);
  lp += __shfl_xor(lp, 32);
  if (g == 0) lsum2[kqh][qrow] = lp;
  LGKM0_BAR();

  float* out_b = out + (size_t)b * N * DK;
#pragma unroll
  for (int j = 0; j < 4; ++j) {
    int qq = vh * 64 + j * 16 + c;
    float rl = 1.f / (lsum2[0][qq] + lsum2[1][qq]);
    int q = q0 + qq;
#pragma unroll
    for (int i = 0; i < 4; ++i) {
      f32x4 o = acc[i][j];
      o[0] *= rl; o[1] *= rl; o[2] *= rl; o[3] *= rl;
      *(f32x4*)&out_b[(size_t)q * DK + vs * 64 + i * 16 + g * 4] = o;
    }
  }
}

// ---------------------------------------------------------------------------
extern "C" void kernel_launch(void* const* d_in, const int* in_sizes, int n_in,
                              void* d_out, int out_size, void* d_ws, size_t ws_size,
                              hipStream_t stream) {
  (void)in_sizes; (void)n_in; (void)out_size; (void)ws_size;
  const float* K  = (const float*)d_in[0];
  const float* Q  = (const float*)d_in[1];
  const float* V  = (const float*)d_in[2];
  const float* Wk = (const float*)d_in[3];
  const float* bk = (const float*)d_in[4];
  const float* Wq = (const float*)d_in[5];
  const float* bq = (const float*)d_in[6];
  float* out = (float*)d_out;

  char* ws = (char*)d_ws;
  short* pq  = (short*)(ws + 0);
  short* pk  = (short*)(ws + ((size_t)4 << 20));
  short* vt  = (short*)(ws + ((size_t)8 << 20));
  short* WqB = (short*)(ws + ((size_t)40 << 20));
  short* WkB = (short*)(ws + ((size_t)40 << 20) + 64 * 512 * 2);

  hipLaunchKernelGGL(wconv_kernel,  dim3(128),  dim3(256), 0, stream, Wk, Wq, WkB, WqB);
  hipLaunchKernelGGL(vtrans_kernel, dim3(4096), dim3(256), 0, stream, V, vt);
  hipLaunchKernelGGL(proj_kernel,   dim3(512),  dim3(512), 0, stream, Q, K, WqB, WkB, bq, bk, pq, pk);
  hipLaunchKernelGGL(flash_kernel,  dim3(256),  dim3(1024), 0, stream, pq, pk, vt, out);
}

// Round 11
// 238.865 us; speedup vs baseline: 1.2805x; 1.1109x over previous
//
#include <hip/hip_runtime.h>
#include <hip/hip_bf16.h>
#include <cstdint>

// ============================================================================
// ScaledDotAttention: out = softmax((Q Wq^T + bq)(K Wk^T + bk)^T / 8) @ V
// B=8, N=4096, DK=512, DM=64.
// R11: R10 pipeline (16 waves @ 4/SIMD, vt dbuf global_load_lds, counted
//      vmcnt(5), reg-staged pk, fixed-max exp2 softmax) spill-proofed:
//      - no divergent role stagger (TLP overlap instead), no lambdas
//      - minimal live registers; target <=64 arch VGPR, zero scratch
//      - sched_barrier pins pk load BEFORE vt DMAs (region-B write then
//        waits only pk; vt(t+1) stays in flight across both barriers)
// ============================================================================

#define DEVINL __device__ __forceinline__

using f32x4  = __attribute__((ext_vector_type(4)))  float;
using bf16x8 = __attribute__((ext_vector_type(8)))  short;
using bf16x4 = __attribute__((ext_vector_type(4)))  short;

constexpr int BATCH = 8;
constexpr int N     = 4096;
constexpr int DK    = 512;
constexpr int DM    = 64;
constexpr int KVB   = 64;
constexpr int QB    = 128;
constexpr int STEPS = N / KVB;       // 64

#define PQ_SCALE 0.18033688011112042f
#define FM 10.0f

DEVINL short cvt_bf16(float x) {
  uint32_t u = __float_as_uint(x);
  uint32_t r = u + 0x7fffu + ((u >> 16) & 1u);
  return (short)(r >> 16);
}

DEVINL uint32_t cvtpk(float lo, float hi) {
  uint32_t r;
  asm("v_cvt_pk_bf16_f32 %0, %1, %2" : "=v"(r) : "v"(lo), "v"(hi));
  return r;
}

DEVINL void async16(void* lds, const void* g) {
  __builtin_amdgcn_global_load_lds(
      (const __attribute__((address_space(1))) uint32_t*)(uintptr_t)g,
      (__attribute__((address_space(3))) uint32_t*)(uint32_t)(uintptr_t)lds,
      16, 0, 0);
}

DEVINL f32x4 mfma16(bf16x8 a, bf16x8 b, f32x4 c) {
  return __builtin_amdgcn_mfma_f32_16x16x32_bf16(a, b, c, 0, 0, 0);
}

#define LGKM0_BAR() do { \
  asm volatile("s_waitcnt lgkmcnt(0)" ::: "memory"); \
  __builtin_amdgcn_s_barrier(); \
} while (0)

// ---------------------------------------------------------------------------
__global__ __launch_bounds__(256) void wconv_kernel(
    const float* __restrict__ Wk, const float* __restrict__ Wq,
    short* __restrict__ WkB, short* __restrict__ WqB) {
  int i = blockIdx.x * 256 + threadIdx.x;
  WkB[i] = cvt_bf16(Wk[i]);
  WqB[i] = cvt_bf16(Wq[i]);
}

// ---------------------------------------------------------------------------
__global__ __launch_bounds__(256) void vtrans_kernel(
    const float* __restrict__ V, short* __restrict__ Vt) {
  int bb = blockIdx.x;
  int b  = bb >> 9;
  int nt = (bb >> 3) & 63;
  int dt = bb & 7;
  int n0 = nt * 64, d0 = dt * 64;
  __shared__ short t_lds[64][80];
  int tid = threadIdx.x;
#pragma unroll
  for (int it = 0; it < 4; ++it) {
    int idx = it * 256 + tid;
    int row = idx >> 4;
    int c4  = idx & 15;
    f32x4 v = *(const f32x4*)&V[((size_t)b * N + n0 + row) * DK + d0 + c4 * 4];
#pragma unroll
    for (int j = 0; j < 4; ++j) t_lds[c4 * 4 + j][row] = cvt_bf16(v[j]);
  }
  __syncthreads();
#pragma unroll
  for (int it = 0; it < 2; ++it) {
    int idx = it * 256 + tid;
    int rd = idx >> 3;
    int ck = idx & 7;
    bf16x8 vv = *(const bf16x8*)&t_lds[rd][ck * 8];
    *(bf16x8*)&Vt[((size_t)b * DK + d0 + rd) * N + n0 + ck * 8] = vv;
  }
}

// ---------------------------------------------------------------------------
__global__ __launch_bounds__(512, 2) void proj_kernel(
    const float* __restrict__ Q, const float* __restrict__ K,
    const short* __restrict__ WqB, const short* __restrict__ WkB,
    const float* __restrict__ bq, const float* __restrict__ bk,
    short* __restrict__ pq, short* __restrict__ pk) {
  bool isK = blockIdx.x >= 256;
  const float* X    = isK ? K : Q;
  const short* W    = isK ? WkB : WqB;
  const float* bias = isK ? bk : bq;
  short* P          = isK ? pk : pq;
  float sc          = isK ? 1.0f : PQ_SCALE;
  int rb = (blockIdx.x & 255) * 128;

  __shared__ short x_lds[128 * 512];
  int tid = threadIdx.x, w = tid >> 6, lane = tid & 63, g = lane >> 4, c = lane & 15;

#pragma unroll
  for (int it = 0; it < 32; ++it) {
    int idx4 = it * 512 + tid;
    int row  = idx4 >> 7;
    int col  = (idx4 & 127) * 4;
    f32x4 v = *(const f32x4*)&X[((size_t)rb + row) * DK + col];
    bf16x4 hb;
#pragma unroll
    for (int j = 0; j < 4; ++j) hb[j] = cvt_bf16(v[j]);
    int scz = (col >> 3) ^ (row & 7);
    *(bf16x4*)&x_lds[row * 512 + scz * 8 + ((col >> 2) & 1) * 4] = hb;
  }
  __syncthreads();

  f32x4 o[4];
#pragma unroll
  for (int mt = 0; mt < 4; ++mt) o[mt] = f32x4{0.f, 0.f, 0.f, 0.f};
  int arow = w * 16 + c;
#pragma unroll
  for (int ks = 0; ks < 16; ++ks) {
    int scz = (ks * 4 + g) ^ (arow & 7);
    bf16x8 a = *(const bf16x8*)&x_lds[arow * 512 + scz * 8];
#pragma unroll
    for (int mt = 0; mt < 4; ++mt) {
      bf16x8 bfr = *(const bf16x8*)&W[(size_t)(mt * 16 + c) * DK + ks * 32 + g * 8];
      o[mt] = mfma16(a, bfr, o[mt]);
    }
  }
#pragma unroll
  for (int mt = 0; mt < 4; ++mt) {
    float bb = bias[mt * 16 + c];
#pragma unroll
    for (int r = 0; r < 4; ++r) {
      int row = rb + w * 16 + g * 4 + r;
      P[(size_t)row * DM + mt * 16 + c] = cvt_bf16((o[mt][r] + bb) * sc);
    }
  }
}

// ---------------------------------------------------------------------------
__global__ __launch_bounds__(1024, 4) void flash_kernel(
    const short* __restrict__ pq, const short* __restrict__ pk,
    const short* __restrict__ vt, float* __restrict__ out) {
  int b  = blockIdx.x & 7;             // batch -> XCD (L2-local vt/pk)
  int qt = blockIdx.x >> 3;            // 0..31
  int q0 = qt * QB;

  int tid = threadIdx.x, w = tid >> 6, lane = tid & 63, g = lane >> 4, c = lane & 15;
  int cs = c & 7;
  int qg = w & 7, kqh = w >> 3;        // qkt role: 16 q x 32 keys
  int qrow = qg * 16 + c;
  int vh = w >> 3, vs = w & 7;         // pv role: 64 vcols x 64 q

  __shared__ short vt_lds[2][DK * KVB];         // 128KB dbuf
  __shared__ short pk_lds[KVB * DM];            //  8KB
  __shared__ short p_lds[QB * KVB];             // 16KB
  __shared__ float lsum2[2][QB];

  // qkt LDS pointers
  const short* pkr0 = pk_lds + (kqh * 32 + c) * 64 + ((g ^ cs) * 8);
  const short* pkr1 = pk_lds + (kqh * 32 + c) * 64 + (((4 + g) ^ cs) * 8);
  short* pw0 = p_lds + qrow * 64 + (((kqh * 4 + 0 + (g >> 1)) ^ cs) * 8) + (g & 1) * 4;
  short* pw1 = p_lds + qrow * 64 + (((kqh * 4 + 2 + (g >> 1)) ^ cs) * 8) + (g & 1) * 4;

  // pv LDS pointers
  const short* pfr0 = p_lds + (vh * 64 + c) * 64 + ((g ^ cs) * 8);
  const short* pfr1 = p_lds + (vh * 64 + c) * 64 + (((4 + g) ^ cs) * 8);
  const short* vfA0 = &vt_lds[0][(vs * 64 + c) * 64 + ((g ^ cs) * 8)];
  const short* vfA1 = &vt_lds[0][(vs * 64 + c) * 64 + (((4 + g) ^ cs) * 8)];
  const short* vfB0 = vfA0 + DK * KVB;
  const short* vfB1 = vfA1 + DK * KVB;

  // vt staging: 4 x async16 per thread
  const short* vt_base = vt + (size_t)b * DK * N;
  int tr = tid >> 3, tc = tid & 7;
  int vt_vo[4];
#pragma unroll
  for (int r = 0; r < 4; ++r)
    vt_vo[r] = (r * 128 + tr) * N + ((tc ^ (tr & 7)) * 8);
  short* vt_dst0 = &vt_lds[0][w * 512];
  short* vt_dst1 = &vt_lds[1][w * 512];

  // pk reg-staging: 8B per thread
  const short* pk_base = pk + (size_t)b * N * DM;
  {
    int prow = tid >> 4, h = tid & 15;
    pk_base += prow * 64 + (((h >> 1) ^ (prow & 7)) * 8) + (h & 1) * 4;
  }
  short* pk_wr = pk_lds + tid * 4;
  bf16x4 pkreg;

  // pq fragments
  const short* pq_row = pq + ((size_t)b * N + q0 + qrow) * DM;
  bf16x8 qf0 = *(const bf16x8*)(pq_row + g * 8);
  bf16x8 qf1 = *(const bf16x8*)(pq_row + 32 + g * 8);

  f32x4 acc[4][4];
#pragma unroll
  for (int i = 0; i < 4; ++i)
#pragma unroll
    for (int j = 0; j < 4; ++j) acc[i][j] = f32x4{0.f, 0.f, 0.f, 0.f};

  float lp = 0.f;
  uint32_t pbu[4];

  // ========================= prolog ========================================
#pragma unroll
  for (int r = 0; r < 4; ++r)
    async16((void*)(vt_dst0 + r * 8192), (const void*)(vt_base + vt_vo[r]));
  vt_base += KVB;
  pkreg = *(const bf16x4*)pk_base;     // pk(0)
  pk_base += KVB * DM;
  *(bf16x4*)pk_wr = pkreg;
  __syncthreads();                     // full drain: vt(0)+pk(0) visible

  // S(0)
#pragma unroll
  for (int s = 0; s < 2; ++s) {
    bf16x8 a0 = *(const bf16x8*)(pkr0 + s * 1024);
    bf16x8 a1 = *(const bf16x8*)(pkr1 + s * 1024);
    f32x4 d = f32x4{-FM, -FM, -FM, -FM};
    d = mfma16(a0, qf0, d);
    d = mfma16(a1, qf1, d);
    float p0 = exp2f(d[0]), p1 = exp2f(d[1]);
    float p2 = exp2f(d[2]), p3 = exp2f(d[3]);
    lp += (p0 + p1) + (p2 + p3);
    pbu[s * 2]     = cvtpk(p0, p1);
    pbu[s * 2 + 1] = cvtpk(p2, p3);
  }
  pkreg = *(const bf16x4*)pk_base;     // pk(1)
  pk_base += KVB * DM;
  LGKM0_BAR();                         // all pk(0) reads done
  *(uint2*)pw0 = uint2{pbu[0], pbu[1]};
  *(uint2*)pw1 = uint2{pbu[2], pbu[3]};
  *(bf16x4*)pk_wr = pkreg;
  LGKM0_BAR();                         // P(0)+pk(1) visible
  __builtin_amdgcn_sched_barrier(0);

  // ========================= main loop: PV(t) + QKT(t+1) ===================
  for (int t = 0; t < STEPS - 1; ++t) {
    int vb = t & 1;
    // pk(t+2) FIRST, pinned before the vt DMAs
    pkreg = *(const bf16x4*)pk_base;
    pk_base += KVB * DM;
    __builtin_amdgcn_sched_barrier(0);
    short* vdst = vb ? vt_dst0 : vt_dst1;
#pragma unroll
    for (int r = 0; r < 4; ++r)
      async16((void*)(vdst + r * 8192), (const void*)(vt_base + vt_vo[r]));
    vt_base += KVB;
    // queue: [vt(t):4, pk(t+2):1, vt(t+1):4] -> drain exactly vt(t)
    asm volatile("s_waitcnt vmcnt(5)" ::: "memory");
    __builtin_amdgcn_sched_barrier(0);

    // ---- QKT(t+1): 4 MFMAs + softmax ----
#pragma unroll
    for (int s = 0; s < 2; ++s) {
      bf16x8 a0 = *(const bf16x8*)(pkr0 + s * 1024);
      bf16x8 a1 = *(const bf16x8*)(pkr1 + s * 1024);
      f32x4 d = f32x4{-FM, -FM, -FM, -FM};
      d = mfma16(a0, qf0, d);
      d = mfma16(a1, qf1, d);
      float p0 = exp2f(d[0]), p1 = exp2f(d[1]);
      float p2 = exp2f(d[2]), p3 = exp2f(d[3]);
      lp += (p0 + p1) + (p2 + p3);
      pbu[s * 2]     = cvtpk(p0, p1);
      pbu[s * 2 + 1] = cvtpk(p2, p3);
    }

    // ---- PV(t): 32 MFMAs ----
    const short* vf0 = vb ? vfB0 : vfA0;
    const short* vf1 = vb ? vfB1 : vfA1;
    __builtin_amdgcn_s_setprio(1);
    {
      bf16x8 vf[4];
#pragma unroll
      for (int i = 0; i < 4; ++i) vf[i] = *(const bf16x8*)(vf0 + i * 1024);
#pragma unroll
      for (int j = 0; j < 4; ++j) {
        bf16x8 pf = *(const bf16x8*)(pfr0 + j * 1024);
#pragma unroll
        for (int i = 0; i < 4; ++i) acc[i][j] = mfma16(vf[i], pf, acc[i][j]);
      }
#pragma unroll
      for (int i = 0; i < 4; ++i) vf[i] = *(const bf16x8*)(vf1 + i * 1024);
#pragma unroll
      for (int j = 0; j < 4; ++j) {
        bf16x8 pf = *(const bf16x8*)(pfr1 + j * 1024);
#pragma unroll
        for (int i = 0; i < 4; ++i) acc[i][j] = mfma16(vf[i], pf, acc[i][j]);
      }
    }
    __builtin_amdgcn_s_setprio(0);

    LGKM0_BAR();                       // barrier 1: all p/pk LDS reads done
    __builtin_amdgcn_sched_barrier(0);

    if (t < STEPS - 2) *(bf16x4*)pk_wr = pkreg;  // waits only pk (vmcnt~4)
    *(uint2*)pw0 = uint2{pbu[0], pbu[1]};
    *(uint2*)pw1 = uint2{pbu[2], pbu[3]};
    LGKM0_BAR();                       // barrier 2: writes visible
    __builtin_amdgcn_sched_barrier(0);
  }

  // ========================= epilog: PV(last) ==============================
  asm volatile("s_waitcnt vmcnt(0)" ::: "memory");
  __builtin_amdgcn_sched_barrier(0);
  {
    int vb = (STEPS - 1) & 1;
    const short* vf0 = vb ? vfB0 : vfA0;
    const short* vf1 = vb ? vfB1 : vfA1;
    bf16x8 vf[4];
#pragma unroll
    for (int i = 0; i < 4; ++i) vf[i] = *(const bf16x8*)(vf0 + i * 1024);
#pragma unroll
    for (int j = 0; j < 4; ++j) {
      bf16x8 pf = *(const bf16x8*)(pfr0 + j * 1024);
#pragma unroll
      for (int i = 0; i < 4; ++i) acc[i][j] = mfma16(vf[i], pf, acc[i][j]);
    }
#pragma unroll
    for (int i = 0; i < 4; ++i) vf[i] = *(const bf16x8*)(vf1 + i * 1024);
#pragma unroll
    for (int j = 0; j < 4; ++j) {
      bf16x8 pf = *(const bf16x8*)(pfr1 + j * 1024);
#pragma unroll
      for (int i = 0; i < 4; ++i) acc[i][j] = mfma16(vf[i], pf, acc[i][j]);
    }
  }

  // l reduce: per-kqh-half partials
  lp += __shfl_xor(lp, 16);
  lp += __shfl_xor(lp, 32);
  if (g == 0) lsum2[kqh][qrow] = lp;
  LGKM0_BAR();

  float* out_b = out + (size_t)b * N * DK;
#pragma unroll
  for (int j = 0; j < 4; ++j) {
    int qq = vh * 64 + j * 16 + c;
    float rl = 1.f / (lsum2[0][qq] + lsum2[1][qq]);
    int q = q0 + qq;
#pragma unroll
    for (int i = 0; i < 4; ++i) {
      f32x4 o = acc[i][j];
      o[0] *= rl; o[1] *= rl; o[2] *= rl; o[3] *= rl;
      *(f32x4*)&out_b[(size_t)q * DK + vs * 64 + i * 16 + g * 4] = o;
    }
  }
}

// ---------------------------------------------------------------------------
extern "C" void kernel_launch(void* const* d_in, const int* in_sizes, int n_in,
                              void* d_out, int out_size, void* d_ws, size_t ws_size,
                              hipStream_t stream) {
  (void)in_sizes; (void)n_in; (void)out_size; (void)ws_size;
  const float* K  = (const float*)d_in[0];
  const float* Q  = (const float*)d_in[1];
  const float* V  = (const float*)d_in[2];
  const float* Wk = (const float*)d_in[3];
  const float* bk = (const float*)d_in[4];
  const float* Wq = (const float*)d_in[5];
  const float* bq = (const float*)d_in[6];
  float* out = (float*)d_out;

  char* ws = (char*)d_ws;
  short* pq  = (short*)(ws + 0);
  short* pk  = (short*)(ws + ((size_t)4 << 20));
  short* vt  = (short*)(ws + ((size_t)8 << 20));
  short* WqB = (short*)(ws + ((size_t)40 << 20));
  short* WkB = (short*)(ws + ((size_t)40 << 20) + 64 * 512 * 2);

  hipLaunchKernelGGL(wconv_kernel,  dim3(128),  dim3(256), 0, stream, Wk, Wq, WkB, WqB);
  hipLaunchKernelGGL(vtrans_kernel, dim3(4096), dim3(256), 0, stream, V, vt);
  hipLaunchKernelGGL(proj_kernel,   dim3(512),  dim3(512), 0, stream, Q, K, WqB, WkB, bq, bk, pq, pk);
  hipLaunchKernelGGL(flash_kernel,  dim3(256),  dim3(1024), 0, stream, pq, pk, vt, out);
}